// Round 1
// baseline (2286.391 us; speedup 1.0000x reference)
//
#include <hip/hip_runtime.h>

// out[n][:] = b[:] ; broadcast bias init (float4 vectorized)
__global__ __launch_bounds__(256) void init_out_kernel(
    float* __restrict__ out, const float* __restrict__ b, long total4)
{
    long i = (long)blockIdx.x * blockDim.x + threadIdx.x;
    if (i >= total4) return;
    int j = (int)(i & 31);               // 128 floats = 32 float4 per row
    ((float4*)out)[i] = ((const float4*)b)[j];
}

// Y = X @ w   (N x 128) = (N x 128)(128 x 128), fp32 vector ALU.
// w fully staged in LDS (64 KB); 32-row X tiles (16 KB); each thread
// computes a 4x4 register block (rows 4*ty+i, cols 4*tx+j).
__global__ __launch_bounds__(256) void gemm_xw_kernel(
    const float* __restrict__ X, const float* __restrict__ w,
    float* __restrict__ Y, int N)
{
    __shared__ float ws[128 * 128];      // 64 KB
    __shared__ float xs[32 * 128];       // 16 KB

    const int tid = threadIdx.x;

    // stage w: 16384 floats = 4096 float4, 16 per thread, coalesced
    for (int i = tid; i < 4096; i += 256)
        ((float4*)ws)[i] = ((const float4*)w)[i];
    __syncthreads();

    const int tx = tid & 31;             // col group: cols 4*tx .. 4*tx+3
    const int ty = tid >> 5;             // row group: rows 4*ty .. 4*ty+3

    const int ntiles = (N + 31) >> 5;    // N = 100000 -> 3125 exact
    for (int tile = blockIdx.x; tile < ntiles; tile += gridDim.x) {
        const int row0 = tile << 5;

        // stage 32x128 X tile: 1024 float4, 4 per thread, fully coalesced
        const float4* Xg = (const float4*)(X + (size_t)row0 * 128);
        for (int i = tid; i < 1024; i += 256)
            ((float4*)xs)[i] = Xg[i];
        __syncthreads();

        float acc[4][4] = {};
        // k-loop in steps of 4 so both operands are ds_read_b128
        for (int k4 = 0; k4 < 32; ++k4) {
            float4 xv[4];
            #pragma unroll
            for (int i = 0; i < 4; ++i)
                xv[i] = *(const float4*)&xs[(ty * 4 + i) * 128 + k4 * 4];
            #pragma unroll
            for (int kk = 0; kk < 4; ++kk) {
                float4 wv = *(const float4*)&ws[(k4 * 4 + kk) * 128 + tx * 4];
                #pragma unroll
                for (int i = 0; i < 4; ++i) {
                    float xvi = (kk == 0) ? xv[i].x : (kk == 1) ? xv[i].y
                              : (kk == 2) ? xv[i].z : xv[i].w;
                    acc[i][0] += xvi * wv.x;
                    acc[i][1] += xvi * wv.y;
                    acc[i][2] += xvi * wv.z;
                    acc[i][3] += xvi * wv.w;
                }
            }
        }

        #pragma unroll
        for (int i = 0; i < 4; ++i) {
            int r = row0 + ty * 4 + i;
            if (r < N)
                *(float4*)(Y + (size_t)r * 128 + tx * 4) =
                    make_float4(acc[i][0], acc[i][1], acc[i][2], acc[i][3]);
        }
        __syncthreads();
    }
}

// For each edge e: out[B[e]][:] += Y[A[e]][:]
// 32 lanes (quarter-wave) per edge, each lane owns 4 consecutive floats:
// coalesced 512B float4 gather per edge + 4 scalar fp32 atomics per lane.
__global__ __launch_bounds__(256) void scatter_add_kernel(
    const float* __restrict__ Y, const int* __restrict__ A,
    const int* __restrict__ B, float* __restrict__ out, int E)
{
    long g = (long)blockIdx.x * blockDim.x + threadIdx.x;
    int e = (int)(g >> 5);
    if (e >= E) return;
    int lane = (int)(g & 31);

    int src = A[e];
    int dst = B[e];

    float4 v = *(const float4*)(Y + (size_t)src * 128 + lane * 4);
    float* o = out + (size_t)dst * 128 + lane * 4;
    atomicAdd(o + 0, v.x);
    atomicAdd(o + 1, v.y);
    atomicAdd(o + 2, v.z);
    atomicAdd(o + 3, v.w);
}

extern "C" void kernel_launch(void* const* d_in, const int* in_sizes, int n_in,
                              void* d_out, int out_size, void* d_ws, size_t ws_size,
                              hipStream_t stream) {
    const float* X = (const float*)d_in[0];
    const int*   A = (const int*)d_in[1];
    const int*   B = (const int*)d_in[2];
    const float* w = (const float*)d_in[3];
    const float* b = (const float*)d_in[4];
    float* out = (float*)d_out;
    float* Y   = (float*)d_ws;           // N x 128 fp32 = 51.2 MB scratch

    const int N = in_sizes[0] / 128;
    const int E = in_sizes[1];

    // 1) out = b (broadcast)
    {
        long total4 = (long)N * 32;
        int grid = (int)((total4 + 255) / 256);
        init_out_kernel<<<grid, 256, 0, stream>>>(out, b, total4);
    }
    // 2) Y = X @ w
    gemm_xw_kernel<<<1024, 256, 0, stream>>>(X, w, Y, N);
    // 3) out[B[e]] += Y[A[e]]
    {
        long threads = (long)E * 32;
        int grid = (int)((threads + 255) / 256);
        scatter_add_kernel<<<grid, 256, 0, stream>>>(Y, A, B, out, E);
    }
}

// Round 2
// 293.847 us; speedup vs baseline: 7.7809x; 7.7809x over previous
//
#include <hip/hip_runtime.h>

// ---------- CSR build ----------

__global__ __launch_bounds__(256) void hist_kernel(
    const int* __restrict__ B, int* __restrict__ hist, int E)
{
    int e = blockIdx.x * 256 + threadIdx.x;
    if (e < E) atomicAdd(&hist[B[e]], 1);
}

// block-local exclusive scan of 256 hist entries; block total -> blockSums
__global__ __launch_bounds__(256) void scan1_kernel(
    const int* __restrict__ hist, int* __restrict__ offsets,
    int* __restrict__ blockSums, int N)
{
    __shared__ int s[256];
    int tid = threadIdx.x;
    int i = blockIdx.x * 256 + tid;
    int v = (i < N) ? hist[i] : 0;
    s[tid] = v;
    __syncthreads();
    for (int off = 1; off < 256; off <<= 1) {
        int t = (tid >= off) ? s[tid - off] : 0;
        __syncthreads();
        s[tid] += t;
        __syncthreads();
    }
    if (i < N) offsets[i] = s[tid] - v;          // exclusive
    if (tid == 255) blockSums[blockIdx.x] = s[255];
}

// exclusive scan of up to 512 block sums, single block
__global__ __launch_bounds__(512) void scan2_kernel(
    int* __restrict__ blockSums, int nb)
{
    __shared__ int s[512];
    int tid = threadIdx.x;
    int v = (tid < nb) ? blockSums[tid] : 0;
    s[tid] = v;
    __syncthreads();
    for (int off = 1; off < 512; off <<= 1) {
        int t = (tid >= off) ? s[tid - off] : 0;
        __syncthreads();
        s[tid] += t;
        __syncthreads();
    }
    if (tid < nb) blockSums[tid] = s[tid] - v;   // exclusive
}

// add scanned block sums; cursor = copy of final offsets (fill mutates it)
__global__ __launch_bounds__(256) void scan3_kernel(
    int* __restrict__ offsets, int* __restrict__ cursor,
    const int* __restrict__ blockSums, int N)
{
    int i = blockIdx.x * 256 + threadIdx.x;
    if (i < N) {
        int o = offsets[i] + blockSums[blockIdx.x];
        offsets[i] = o;
        cursor[i]  = o;
    }
}

// scatter edge sources into CSR order; after this cursor[i] == row end
__global__ __launch_bounds__(256) void fill_kernel(
    const int* __restrict__ A, const int* __restrict__ B,
    int* __restrict__ cursor, int* __restrict__ csr_src, int E)
{
    int e = blockIdx.x * 256 + threadIdx.x;
    if (e < E) {
        int pos = atomicAdd(&cursor[B[e]], 1);
        csr_src[pos] = A[e];
    }
}

// ---------- aggregation: out[n] = sum over in-edges of X[src] ----------
// 32 lanes per node, each lane owns 4 consecutive floats (512B coalesced row).
__global__ __launch_bounds__(256) void agg_kernel(
    const float* __restrict__ X, const int* __restrict__ offsets,
    const int* __restrict__ cursor, const int* __restrict__ csr_src,
    float* __restrict__ out, int N)
{
    long g = (long)blockIdx.x * 256 + threadIdx.x;
    int node = (int)(g >> 5);
    if (node >= N) return;
    int lane = (int)(g & 31);

    int s = offsets[node];
    int e = cursor[node];                 // end (fill advanced it by degree)
    float4 acc = make_float4(0.f, 0.f, 0.f, 0.f);
    for (int j = s; j < e; ++j) {
        int src = csr_src[j];
        float4 v = *(const float4*)(X + (size_t)src * 128 + lane * 4);
        acc.x += v.x; acc.y += v.y; acc.z += v.z; acc.w += v.w;
    }
    *(float4*)(out + (size_t)node * 128 + lane * 4) = acc;
}

// ---------- in-place GEMM: io = io @ w + b ----------
// 32-row tiles, w fully in LDS, 4x4 register block per thread.
// #pragma unroll 1 on the k-loop: R1's full unroll spilled (VGPR=256,
// 1.85 GB scratch FETCH).
__global__ __launch_bounds__(256) void gemm_inplace_kernel(
    float* __restrict__ io, const float* __restrict__ w,
    const float* __restrict__ b, int N)
{
    __shared__ float ws[128 * 128];      // 64 KB
    __shared__ float xs[32 * 128];       // 16 KB

    const int tid = threadIdx.x;
    for (int i = tid; i < 4096; i += 256)
        ((float4*)ws)[i] = ((const float4*)w)[i];

    const int row0 = blockIdx.x * 32;
    const int nrows = min(32, N - row0);
    const float4* Xg = (const float4*)(io + (size_t)row0 * 128);
    for (int i = tid; i < nrows * 32; i += 256)
        ((float4*)xs)[i] = Xg[i];
    __syncthreads();

    const int tx = tid & 31;             // cols 4*tx .. 4*tx+3
    const int ty = tid >> 5;             // rows 4*ty .. 4*ty+3

    float acc[4][4] = {};
    #pragma unroll 1
    for (int k4 = 0; k4 < 32; ++k4) {
        float4 wv[4];
        #pragma unroll
        for (int kk = 0; kk < 4; ++kk)
            wv[kk] = *(const float4*)&ws[(k4 * 4 + kk) * 128 + tx * 4];
        #pragma unroll
        for (int i = 0; i < 4; ++i) {
            float4 xv = *(const float4*)&xs[(ty * 4 + i) * 128 + k4 * 4];
            acc[i][0] += xv.x * wv[0].x + xv.y * wv[1].x + xv.z * wv[2].x + xv.w * wv[3].x;
            acc[i][1] += xv.x * wv[0].y + xv.y * wv[1].y + xv.z * wv[2].y + xv.w * wv[3].y;
            acc[i][2] += xv.x * wv[0].z + xv.y * wv[1].z + xv.z * wv[2].z + xv.w * wv[3].z;
            acc[i][3] += xv.x * wv[0].w + xv.y * wv[1].w + xv.z * wv[2].w + xv.w * wv[3].w;
        }
    }

    float4 bv = ((const float4*)b)[tx];
    #pragma unroll
    for (int i = 0; i < 4; ++i) {
        int r = row0 + ty * 4 + i;
        if (r < N)
            *(float4*)(io + (size_t)r * 128 + tx * 4) =
                make_float4(acc[i][0] + bv.x, acc[i][1] + bv.y,
                            acc[i][2] + bv.z, acc[i][3] + bv.w);
    }
}

extern "C" void kernel_launch(void* const* d_in, const int* in_sizes, int n_in,
                              void* d_out, int out_size, void* d_ws, size_t ws_size,
                              hipStream_t stream) {
    const float* X = (const float*)d_in[0];
    const int*   A = (const int*)d_in[1];
    const int*   B = (const int*)d_in[2];
    const float* w = (const float*)d_in[3];
    const float* b = (const float*)d_in[4];
    float* out = (float*)d_out;

    const int N = in_sizes[0] / 128;
    const int E = in_sizes[1];

    // ws layout (ints): hist[N] | offsets[N] | cursor[N] | blockSums[512] | csr_src[E]
    char* wsb = (char*)d_ws;
    int* hist      = (int*)(wsb);
    int* offsets   = (int*)(wsb + (size_t)4 * N);
    int* cursor    = (int*)(wsb + (size_t)8 * N);
    int* blockSums = (int*)(wsb + (size_t)12 * N);
    int* csr_src   = (int*)(wsb + (size_t)12 * N + 2048);

    const int nbN = (N + 255) / 256;     // 391 for N=100000 (must be <= 512)
    const int nbE = (E + 255) / 256;

    hipMemsetAsync(hist, 0, (size_t)4 * N, stream);
    hist_kernel<<<nbE, 256, 0, stream>>>(B, hist, E);
    scan1_kernel<<<nbN, 256, 0, stream>>>(hist, offsets, blockSums, N);
    scan2_kernel<<<1, 512, 0, stream>>>(blockSums, nbN);
    scan3_kernel<<<nbN, 256, 0, stream>>>(offsets, cursor, blockSums, N);
    fill_kernel<<<nbE, 256, 0, stream>>>(A, B, cursor, csr_src, E);

    {   // out[n] = segment_sum(X[A])[n]
        long threads = (long)N * 32;
        int grid = (int)((threads + 255) / 256);
        agg_kernel<<<grid, 256, 0, stream>>>(X, offsets, cursor, csr_src, out, N);
    }
    {   // out = out @ w + b, in place
        int grid = (N + 31) / 32;
        gemm_inplace_kernel<<<grid, 256, 0, stream>>>(out, w, b, N);
    }
}

// Round 3
// 265.402 us; speedup vs baseline: 8.6148x; 1.1072x over previous
//
#include <hip/hip_runtime.h>
#include <hip/hip_bf16.h>

typedef short s16x8 __attribute__((ext_vector_type(8)));
typedef float f32x4 __attribute__((ext_vector_type(4)));

static __device__ inline unsigned short f2bf(float f) {
    __hip_bfloat16 h = __float2bfloat16(f);
    return *reinterpret_cast<unsigned short*>(&h);
}

// ---------- CSR build ----------

__global__ __launch_bounds__(256) void hist_kernel(
    const int* __restrict__ B, int* __restrict__ hist, int E)
{
    int e = blockIdx.x * 256 + threadIdx.x;
    if (e < E) atomicAdd(&hist[B[e]], 1);
}

__global__ __launch_bounds__(256) void scan1_kernel(
    const int* __restrict__ hist, int* __restrict__ offsets,
    int* __restrict__ blockSums, int N)
{
    __shared__ int s[256];
    int tid = threadIdx.x;
    int i = blockIdx.x * 256 + tid;
    int v = (i < N) ? hist[i] : 0;
    s[tid] = v;
    __syncthreads();
    for (int off = 1; off < 256; off <<= 1) {
        int t = (tid >= off) ? s[tid - off] : 0;
        __syncthreads();
        s[tid] += t;
        __syncthreads();
    }
    if (i < N) offsets[i] = s[tid] - v;
    if (tid == 255) blockSums[blockIdx.x] = s[255];
}

__global__ __launch_bounds__(512) void scan2_kernel(
    int* __restrict__ blockSums, int nb)
{
    __shared__ int s[512];
    int tid = threadIdx.x;
    int v = (tid < nb) ? blockSums[tid] : 0;
    s[tid] = v;
    __syncthreads();
    for (int off = 1; off < 512; off <<= 1) {
        int t = (tid >= off) ? s[tid - off] : 0;
        __syncthreads();
        s[tid] += t;
        __syncthreads();
    }
    if (tid < nb) blockSums[tid] = s[tid] - v;
}

__global__ __launch_bounds__(256) void scan3_kernel(
    int* __restrict__ offsets, int* __restrict__ cursor,
    const int* __restrict__ blockSums, int N)
{
    int i = blockIdx.x * 256 + threadIdx.x;
    if (i < N) {
        int o = offsets[i] + blockSums[blockIdx.x];
        offsets[i] = o;
        cursor[i]  = o;
    }
}

__global__ __launch_bounds__(256) void fill_kernel(
    const int* __restrict__ A, const int* __restrict__ B,
    int* __restrict__ cursor, int* __restrict__ csr_src, int E)
{
    int e = blockIdx.x * 256 + threadIdx.x;
    if (e < E) {
        int pos = atomicAdd(&cursor[B[e]], 1);
        csr_src[pos] = A[e];
    }
}

// ---------- w transpose + bf16 convert: wT[n][k] = bf16(w[k][n]) ----------
__global__ __launch_bounds__(256) void wtrans_kernel(
    const float* __restrict__ w, unsigned short* __restrict__ wT)
{
    int i = blockIdx.x * 256 + threadIdx.x;   // 16384 threads
    int n = i >> 7, k = i & 127;
    wT[i] = f2bf(w[k * 128 + n]);             // write coalesced, read L2-hot
}

// ---------- aggregation: aggb[n][:] = bf16( sum over in-edges X[src][:] ) ----
// One full wave (64 lanes) per node; lane owns 2 floats (8B) of the 512B row.
// csr_src values prefetched 64-at-a-time into lanes, broadcast via __shfl.
__global__ __launch_bounds__(256) void agg_kernel(
    const float* __restrict__ X, const int* __restrict__ offsets,
    const int* __restrict__ ends, const int* __restrict__ csr_src,
    unsigned short* __restrict__ aggb, int N)
{
    int g = blockIdx.x * 256 + threadIdx.x;
    int node = g >> 6;
    if (node >= N) return;
    int lane = g & 63;

    int s = offsets[node];
    int e = ends[node];
    int deg = e - s;

    int idx = s + lane;
    int src_l = (idx < e) ? csr_src[idx] : 0;

    float2 acc = make_float2(0.f, 0.f);
    for (int j = 0; j < deg; ++j) {
        int jm = j & 63;
        if (j != 0 && jm == 0) {
            idx += 64;
            src_l = (idx < e) ? csr_src[idx] : 0;
        }
        int src = __shfl(src_l, jm);
        float2 v = *(const float2*)(X + (size_t)src * 128 + lane * 2);
        acc.x += v.x; acc.y += v.y;
    }

    unsigned int pk = (unsigned int)f2bf(acc.x) | ((unsigned int)f2bf(acc.y) << 16);
    *(unsigned int*)(aggb + (size_t)node * 128 + lane * 2) = pk;
}

// ---------- GEMM: out = aggb @ w + b via bf16 MFMA, no LDS ----------
// Block = 4 waves, 64 rows (16/wave). A-frags from global aggb (16B/lane
// contiguous); B-frags from L2-resident wT (wave touches 16 full lines/load).
// 16x16x32 layouts (m89-verified): A[m=lane&15][k=(lane>>4)*8+j],
// B[k=(lane>>4)*8+j][n=lane&15], C col=lane&15 row=(lane>>4)*4+reg.
__global__ __launch_bounds__(256) void gemm_mfma_kernel(
    const unsigned short* __restrict__ aggb, const unsigned short* __restrict__ wT,
    const float* __restrict__ b, float* __restrict__ out, int N)
{
    const int tid  = threadIdx.x;
    const int wave = tid >> 6;
    const int lane = tid & 63;
    const int m = lane & 15;
    const int q = lane >> 4;

    const int row0 = blockIdx.x * 64 + wave * 16;

    int arow = row0 + m;
    if (arow >= N) arow = N - 1;          // clamp; dup loads, stores guarded
    const unsigned short* abase = aggb + (size_t)arow * 128 + q * 8;

    s16x8 a[4];
    #pragma unroll
    for (int s = 0; s < 4; ++s)
        a[s] = *(const s16x8*)(abase + s * 32);

    f32x4 acc[8] = {};
    #pragma unroll
    for (int s = 0; s < 4; ++s) {
        #pragma unroll
        for (int c = 0; c < 8; ++c) {
            s16x8 bf = *(const s16x8*)&wT[(size_t)(c * 16 + m) * 128 + s * 32 + q * 8];
            acc[c] = __builtin_amdgcn_mfma_f32_16x16x32_bf16(a[s], bf, acc[c], 0, 0, 0);
        }
    }

    const int r0 = row0 + q * 4;
    #pragma unroll
    for (int c = 0; c < 8; ++c) {
        int col = c * 16 + m;
        float bias = b[col];
        #pragma unroll
        for (int r = 0; r < 4; ++r) {
            int row = r0 + r;
            if (row < N)
                out[(size_t)row * 128 + col] = acc[c][r] + bias;
        }
    }
}

extern "C" void kernel_launch(void* const* d_in, const int* in_sizes, int n_in,
                              void* d_out, int out_size, void* d_ws, size_t ws_size,
                              hipStream_t stream) {
    const float* X = (const float*)d_in[0];
    const int*   A = (const int*)d_in[1];
    const int*   B = (const int*)d_in[2];
    const float* w = (const float*)d_in[3];
    const float* b = (const float*)d_in[4];
    float* out = (float*)d_out;

    const int N = in_sizes[0] / 128;
    const int E = in_sizes[1];

    // ws layout: hist[N] | offsets[N] | cursor[N] | blockSums[512] | wT[16384 u16]
    //            | (256B align) aggb[N*128 u16] | csr_src[E]
    char* wsb = (char*)d_ws;
    size_t off = 0;
    int* hist      = (int*)(wsb + off); off += (size_t)4 * N;
    int* offsets   = (int*)(wsb + off); off += (size_t)4 * N;
    int* cursor    = (int*)(wsb + off); off += (size_t)4 * N;
    int* blockSums = (int*)(wsb + off); off += 2048;
    unsigned short* wT = (unsigned short*)(wsb + off); off += 32768;
    off = (off + 255) & ~(size_t)255;
    unsigned short* aggb = (unsigned short*)(wsb + off); off += (size_t)N * 256;
    off = (off + 255) & ~(size_t)255;
    int* csr_src   = (int*)(wsb + off);

    const int nbN = (N + 255) / 256;      // 391 (<= 512 for scan2)
    const int nbE = (E + 255) / 256;

    hipMemsetAsync(hist, 0, (size_t)4 * N, stream);
    hist_kernel<<<nbE, 256, 0, stream>>>(B, hist, E);
    scan1_kernel<<<nbN, 256, 0, stream>>>(hist, offsets, blockSums, N);
    scan2_kernel<<<1, 512, 0, stream>>>(blockSums, nbN);
    scan3_kernel<<<nbN, 256, 0, stream>>>(offsets, cursor, blockSums, N);
    fill_kernel<<<nbE, 256, 0, stream>>>(A, B, cursor, csr_src, E);
    wtrans_kernel<<<64, 256, 0, stream>>>(w, wT);

    {   // aggb[n] = bf16(segment_sum(X[A])[n]) — one wave per node
        long threads = (long)N * 64;
        int grid = (int)((threads + 255) / 256);
        agg_kernel<<<grid, 256, 0, stream>>>(X, offsets, cursor, csr_src, aggb, N);
    }
    {   // out = aggb @ w + b
        int grid = (N + 63) / 64;
        gemm_mfma_kernel<<<grid, 256, 0, stream>>>(aggb, wT, b, out, N);
    }
}